// Round 1
// baseline (140.189 us; speedup 1.0000x reference)
//
#include <hip/hip_runtime.h>
#include <hip/hip_bf16.h>
#include <math.h>

#define N 8192
#define D 128
#define BI 128
#define BJ 64
#define NJS 8           // j-slices (grid.y)
#define JT 16           // j-tiles per block (NJS*JT*BJ == N)
#define BLOCK 512

#define LOG_2PI 1.8378770664093453f

typedef __attribute__((ext_vector_type(8))) short bf16x8;
typedef __attribute__((ext_vector_type(4))) float f32x4;

// ws layout (floats)
#define SQX_OFF 0
#define SQY_OFF 8192
#define PART_OFF 16384
#define PART_PER_BLOCK (3 * BI)            // 384
#define NBLK (64 * NJS)                    // 512 main blocks
#define BSUM_OFF (PART_OFF + NBLK * PART_PER_BLOCK)   // 212992 (+64) floats total

__device__ __forceinline__ unsigned short f2bf(float f) {
    unsigned int x = __float_as_uint(f);
    unsigned int r = (x + 0x7fffu + ((x >> 16) & 1u)) >> 16;  // RNE
    return (unsigned short)r;
}

// ---------------- row squared norms ----------------
__global__ void sq_kernel(const float* __restrict__ X, const float* __restrict__ Y,
                          float* __restrict__ ws) {
    int tid = threadIdx.x;
    int rowg = blockIdx.x * 8 + (tid >> 5);   // 0..16383 (X rows then Y rows)
    int lane = tid & 31;
    const float* src = (rowg < N) ? (X + (size_t)rowg * D) : (Y + (size_t)(rowg - N) * D);
    float4 v = reinterpret_cast<const float4*>(src)[lane];
    float s = v.x * v.x + v.y * v.y + v.z * v.z + v.w * v.w;
#pragma unroll
    for (int m = 16; m; m >>= 1) s += __shfl_xor(s, m, 64);
    if (lane == 0) {
        if (rowg < N) ws[SQX_OFF + rowg] = s;
        else          ws[SQY_OFF + rowg - N] = s;
    }
}

// ---------------- main fused kernel ----------------
__launch_bounds__(BLOCK)
__global__ void kde_main(const float* __restrict__ X, const float* __restrict__ Y,
                         const float* __restrict__ sjp, const float* __restrict__ sxp,
                         const float* __restrict__ syp, float* __restrict__ ws) {
    __shared__ unsigned short Xi[BI][D];   // 32 KB, bf16 bits, XOR-swizzled 16B slots
    __shared__ unsigned short Yi[BI][D];   // 32 KB
    __shared__ unsigned short Xj[BJ][D];   // 16 KB
    __shared__ unsigned short Yj[BJ][D];   // 16 KB
    __shared__ float sqix[BI], sqiy[BI], sqjx[BJ], sqjy[BJ];
    __shared__ float red[2][BI][3];

    const int tid  = threadIdx.x;
    const int lane = tid & 63;
    const int wid  = tid >> 6;
    const int wr   = wid >> 1;     // 0..3 : 32-row band
    const int wc   = wid & 1;      // 0..1 : 32-col half
    const int itile = blockIdx.x;
    const int js    = blockIdx.y;
    const int i0    = itile * BI;

    const float sx = *sxp, sy = *syp, sj = *sjp;
    const float cx = -0.5f / (sx * sx);
    const float cy = -0.5f / (sy * sy);
    const float cj = -0.5f / (sj * sj);

    // ---- stage Xi, Yi (once per block) ----
    for (int c = tid; c < 4096; c += BLOCK) {
        int t    = c >> 11;        // 0: X, 1: Y
        int row  = (c >> 4) & 127;
        int col8 = c & 15;
        const float* src = (t ? Y : X) + (size_t)(i0 + row) * D + col8 * 8;
        const float4* s4 = reinterpret_cast<const float4*>(src);
        float4 a = s4[0], b = s4[1];
        unsigned int w0 = (unsigned int)f2bf(a.x) | ((unsigned int)f2bf(a.y) << 16);
        unsigned int w1 = (unsigned int)f2bf(a.z) | ((unsigned int)f2bf(a.w) << 16);
        unsigned int w2 = (unsigned int)f2bf(b.x) | ((unsigned int)f2bf(b.y) << 16);
        unsigned int w3 = (unsigned int)f2bf(b.z) | ((unsigned int)f2bf(b.w) << 16);
        uint4 pk = make_uint4(w0, w1, w2, w3);
        int slot = col8 ^ (row & 7);
        unsigned short* dst = (t ? &Yi[0][0] : &Xi[0][0]) + row * D + (slot << 3);
        *reinterpret_cast<uint4*>(dst) = pk;
    }
    if (tid < 2 * BI) {
        int r = tid & (BI - 1);
        if (tid < BI) sqix[r] = ws[SQX_OFF + i0 + r];
        else          sqiy[r] = ws[SQY_OFF + i0 + r];
    }

    float p[2][4][3];
#pragma unroll
    for (int a = 0; a < 2; ++a)
#pragma unroll
        for (int b = 0; b < 4; ++b)
#pragma unroll
            for (int ch = 0; ch < 3; ++ch) p[a][b][ch] = 0.0f;

    for (int jt = 0; jt < JT; ++jt) {
        const int j0 = (js * JT + jt) * BJ;
        __syncthreads();   // protect LDS (Xi visible on first iter; Xj reuse after)

        // ---- stage Xj, Yj ----
        for (int c = tid; c < 2048; c += BLOCK) {
            int t    = c >> 10;
            int row  = (c >> 4) & 63;
            int col8 = c & 15;
            const float* src = (t ? Y : X) + (size_t)(j0 + row) * D + col8 * 8;
            const float4* s4 = reinterpret_cast<const float4*>(src);
            float4 a = s4[0], b = s4[1];
            unsigned int w0 = (unsigned int)f2bf(a.x) | ((unsigned int)f2bf(a.y) << 16);
            unsigned int w1 = (unsigned int)f2bf(a.z) | ((unsigned int)f2bf(a.w) << 16);
            unsigned int w2 = (unsigned int)f2bf(b.x) | ((unsigned int)f2bf(b.y) << 16);
            unsigned int w3 = (unsigned int)f2bf(b.z) | ((unsigned int)f2bf(b.w) << 16);
            uint4 pk = make_uint4(w0, w1, w2, w3);
            int slot = col8 ^ (row & 7);
            unsigned short* dst = (t ? &Yj[0][0] : &Xj[0][0]) + row * D + (slot << 3);
            *reinterpret_cast<uint4*>(dst) = pk;
        }
        if (tid < 2 * BJ) {
            int r = tid & (BJ - 1);
            if (tid < BJ) sqjx[r] = ws[SQX_OFF + j0 + r];
            else          sqjy[r] = ws[SQY_OFF + j0 + r];
        }
        __syncthreads();

        // ---- two GEMMs: Gx = Xi·Xj^T, Gy = Yi·Yj^T ----
        f32x4 ax[2][2], ay[2][2];
#pragma unroll
        for (int rf = 0; rf < 2; ++rf)
#pragma unroll
            for (int cf = 0; cf < 2; ++cf) {
                ax[rf][cf] = (f32x4){0.f, 0.f, 0.f, 0.f};
                ay[rf][cf] = (f32x4){0.f, 0.f, 0.f, 0.f};
            }

#pragma unroll
        for (int kk = 0; kk < 4; ++kk) {
            const int k0 = kk * 4 + (lane >> 4);   // 16B-slot index along K
            bf16x8 afx[2], afy[2], bfx[2], bfy[2];
#pragma unroll
            for (int rf = 0; rf < 2; ++rf) {
                int r = wr * 32 + rf * 16 + (lane & 15);
                int slot = k0 ^ (r & 7);
                afx[rf] = *reinterpret_cast<const bf16x8*>(&Xi[r][slot << 3]);
                afy[rf] = *reinterpret_cast<const bf16x8*>(&Yi[r][slot << 3]);
            }
#pragma unroll
            for (int cf = 0; cf < 2; ++cf) {
                int r = wc * 32 + cf * 16 + (lane & 15);
                int slot = k0 ^ (r & 7);
                bfx[cf] = *reinterpret_cast<const bf16x8*>(&Xj[r][slot << 3]);
                bfy[cf] = *reinterpret_cast<const bf16x8*>(&Yj[r][slot << 3]);
            }
#pragma unroll
            for (int rf = 0; rf < 2; ++rf)
#pragma unroll
                for (int cf = 0; cf < 2; ++cf) {
                    ax[rf][cf] = __builtin_amdgcn_mfma_f32_16x16x32_bf16(afx[rf], bfx[cf], ax[rf][cf], 0, 0, 0);
                    ay[rf][cf] = __builtin_amdgcn_mfma_f32_16x16x32_bf16(afy[rf], bfy[cf], ay[rf][cf], 0, 0, 0);
                }
        }

        // ---- fused combine: 3-channel exp accumulation ----
#pragma unroll
        for (int rf = 0; rf < 2; ++rf) {
#pragma unroll
            for (int reg = 0; reg < 4; ++reg) {
                const int row = wr * 32 + rf * 16 + ((lane >> 4) << 2) + reg;
                const float sxi = sqix[row];
                const float syi = sqiy[row];
#pragma unroll
                for (int cf = 0; cf < 2; ++cf) {
                    const int col = wc * 32 + cf * 16 + (lane & 15);
                    float gx = ax[rf][cf][reg];
                    float gy = ay[rf][cf][reg];
                    float d2x = fmaxf(sxi + sqjx[col] - 2.0f * gx, 0.0f);
                    float d2y = fmaxf(syi + sqjy[col] - 2.0f * gy, 0.0f);
                    p[rf][reg][0] += __expf(d2x * cx);
                    p[rf][reg][1] += __expf(d2y * cy);
                    p[rf][reg][2] += __expf((d2x + d2y) * cj);
                }
            }
        }
    }

    // ---- reduce partials: over 16 col-lanes, then across wc halves ----
#pragma unroll
    for (int rf = 0; rf < 2; ++rf)
#pragma unroll
        for (int reg = 0; reg < 4; ++reg)
#pragma unroll
            for (int ch = 0; ch < 3; ++ch) {
                float v = p[rf][reg][ch];
#pragma unroll
                for (int m = 1; m < 16; m <<= 1) v += __shfl_xor(v, m, 64);
                p[rf][reg][ch] = v;
            }

    if ((lane & 15) == 0) {
#pragma unroll
        for (int rf = 0; rf < 2; ++rf)
#pragma unroll
            for (int reg = 0; reg < 4; ++reg) {
                int row = wr * 32 + rf * 16 + ((lane >> 4) << 2) + reg;
#pragma unroll
                for (int ch = 0; ch < 3; ++ch) red[wc][row][ch] = p[rf][reg][ch];
            }
    }
    __syncthreads();

    if (tid < BI) {
        int b = itile * NJS + js;
        size_t base = PART_OFF + (size_t)b * PART_PER_BLOCK;
#pragma unroll
        for (int ch = 0; ch < 3; ++ch)
            ws[base + ch * BI + tid] = red[0][tid][ch] + red[1][tid][ch];
    }
}

// ---------------- per-row lp + partial loss ----------------
__global__ void lp_reduce(const float* __restrict__ sjp, const float* __restrict__ sxp,
                          const float* __restrict__ syp, float* __restrict__ ws) {
    int b = blockIdx.x;    // 64 blocks, 128 rows each
    int t = threadIdx.x;   // 128 threads
    float Sx = 0.f, Sy = 0.f, Sj = 0.f;
    for (int s = 0; s < NJS; ++s) {
        size_t base = PART_OFF + (size_t)(b * NJS + s) * PART_PER_BLOCK;
        Sx += ws[base + 0 * BI + t];
        Sy += ws[base + 1 * BI + t];
        Sj += ws[base + 2 * BI + t];
    }
    float sx = *sxp, sy = *syp, sj = *sjp;
    float logN = logf((float)N);
    float lpx = logf(Sx) - (float)D * logf(sx) - 0.5f * (float)D * LOG_2PI - logN;
    float lpy = logf(Sy) - (float)D * logf(sy) - 0.5f * (float)D * LOG_2PI - logN;
    float lpj = logf(Sj) - 2.0f * (float)D * logf(sj) - (float)D * LOG_2PI - logN;
    float I = expf(lpj) * (lpj - lpx - lpy);
#pragma unroll
    for (int m = 1; m < 64; m <<= 1) I += __shfl_xor(I, m, 64);
    __shared__ float w0[2];
    if ((t & 63) == 0) w0[t >> 6] = I;
    __syncthreads();
    if (t == 0) ws[BSUM_OFF + b] = w0[0] + w0[1];
}

__global__ void final_reduce(float* __restrict__ ws, float* __restrict__ out) {
    int t = threadIdx.x;   // 64
    float v = ws[BSUM_OFF + t];
#pragma unroll
    for (int m = 1; m < 64; m <<= 1) v += __shfl_xor(v, m, 64);
    if (t == 0) out[0] = -v;
}

extern "C" void kernel_launch(void* const* d_in, const int* in_sizes, int n_in,
                              void* d_out, int out_size, void* d_ws, size_t ws_size,
                              hipStream_t stream) {
    const float* X  = (const float*)d_in[0];
    const float* Y  = (const float*)d_in[1];
    const float* sj = (const float*)d_in[2];
    const float* sx = (const float*)d_in[3];
    const float* sy = (const float*)d_in[4];
    float* out = (float*)d_out;
    float* ws  = (float*)d_ws;

    sq_kernel<<<dim3(2048), dim3(256), 0, stream>>>(X, Y, ws);
    kde_main<<<dim3(64, NJS), dim3(BLOCK), 0, stream>>>(X, Y, sj, sx, sy, ws);
    lp_reduce<<<dim3(64), dim3(128), 0, stream>>>(sj, sx, sy, ws);
    final_reduce<<<dim3(1), dim3(64), 0, stream>>>(ws, out);
}